// Round 14
// baseline (219.501 us; speedup 1.0000x reference)
//
#include <hip/hip_runtime.h>

// MHA forward. L=S=1024, N=4, E=1024, H=16, hd=64, B=N*H=64, M=L*N=4096
// Inputs fp32, outputs fp32 (out0=attn_output 4.19M, out1=attn_weights 4.19M @+4194304).
// Round 20: T1 XCD co-location for the attention kernels (index remap only).
// attn_ctx: old mapping hwid=b*8+lt -> hwid%8=lt put the 8 blocks sharing one
// head's K/V on 8 DIFFERENT XCDs (8x L2 duplication, ~14MB excess FETCH).
// New: XCD x owns b in [8x,8x+8) (K/V working set 2MB <= 4MB L2/XCD).
// attn_w: XCD x owns (n,st) combos [8x,8x+8) with lt fastest (K-slab 1MB +
// qh[n] 2MB <= L2; 16 consecutive blocks share each K-slab).
// Bijective permutations; numerics bit-identical. All sync structures
// unchanged from r19 (verified 216us; best 213.9).
typedef unsigned short u16;
typedef __attribute__((ext_vector_type(8))) short short8;   // 8 bf16 (4 VGPRs)
typedef __attribute__((ext_vector_type(4))) float f32x4;    // MFMA accumulator

__device__ __forceinline__ u16 f2bf(float f) {  // RNE
  unsigned int i = __float_as_uint(f);
  i += 0x7fffu + ((i >> 16) & 1u);
  return (u16)(i >> 16);
}

__device__ __forceinline__ short8 cvt8(const float* p) {
  float4 a = ((const float4*)p)[0];
  float4 b = ((const float4*)p)[1];
  short8 r;
  r[0] = (short)f2bf(a.x); r[1] = (short)f2bf(a.y);
  r[2] = (short)f2bf(a.z); r[3] = (short)f2bf(a.w);
  r[4] = (short)f2bf(b.x); r[5] = (short)f2bf(b.y);
  r[6] = (short)f2bf(b.z); r[7] = (short)f2bf(b.w);
  return r;
}

// ---------------------------------------------------------------------------
// Kernel 0: one-shot fp32 -> bf16 conversion of q/k/v/W_in/W_out. (unchanged)
// ---------------------------------------------------------------------------
__global__ __launch_bounds__(256) void convert_bf16(
    const float* __restrict__ q, const float* __restrict__ k,
    const float* __restrict__ v, const float* __restrict__ Wi,
    const float* __restrict__ Wo,
    u16* __restrict__ qb, u16* __restrict__ kb, u16* __restrict__ vb,
    u16* __restrict__ Wib, u16* __restrict__ Wob)
{
  const float* src; u16* dst; int len8;
  switch (blockIdx.y) {
    case 0:  src = q;  dst = qb;  len8 = 524288; break;  // 4M elts
    case 1:  src = k;  dst = kb;  len8 = 524288; break;
    case 2:  src = v;  dst = vb;  len8 = 524288; break;
    case 3:  src = Wi; dst = Wib; len8 = 393216; break;  // 3M elts
    default: src = Wo; dst = Wob; len8 = 131072; break;  // 1M elts
  }
  int stride = gridDim.x * 256;
  for (int i = blockIdx.x * 256 + threadIdx.x; i < len8; i += stride)
    *(short8*)(dst + (size_t)i * 8) = cvt8(src + (size_t)i * 8);
}

// ---------------------------------------------------------------------------
// Kernel 1: packed QKV projection. (r13, verified)
// 128x128 tile, BK=32, 3-buffer counted-vmcnt pipeline, coalesced epilogue.
// ---------------------------------------------------------------------------
__global__ __launch_bounds__(256) void qkv_gemm(
    const u16* __restrict__ qb, const u16* __restrict__ kb,
    const u16* __restrict__ vb, const u16* __restrict__ W,
    const float* __restrict__ bias,
    u16* __restrict__ qh, u16* __restrict__ kh, u16* __restrict__ vt)
{
  __shared__ __align__(16) u16 SH[24576];

  const int tid  = threadIdx.x;
  const int wave = tid >> 6;
  const int lane = tid & 63;
  const int r    = lane & 15;
  const int q4   = lane >> 4;
  const int wm   = wave >> 1;
  const int wn   = wave & 1;

  const int orig = blockIdx.y * 24 + blockIdx.x;
  const int nid  = (orig & 7) * 96 + (orig >> 3);
  const int mt   = nid / 24;
  const int jt   = nid - mt * 24;
  const int src  = jt >> 3;
  const u16* X = (src == 0) ? qb : (src == 1) ? kb : vb;
  const int m0 = mt * 128;
  const int j0 = jt * 128;

  const int lrow = lane >> 2;
  const int lchk = ((lane & 3) ^ ((lane >> 3) & 3)) << 4;
  const char* Xc = (const char*)X;
  const char* Wc = (const char*)W;
  const int fchk = (q4 ^ ((r >> 1) & 3)) << 3;

  f32x4 acc[4][4];
  #pragma unroll
  for (int a = 0; a < 4; ++a)
    #pragma unroll
    for (int b = 0; b < 4; ++b)
      acc[a][b] = (f32x4){0.f, 0.f, 0.f, 0.f};

  auto STAGE = [&](int buf, int kt) {   // 4 gload_lds per wave
    const int kbyte = kt * 64;
    u16* Ad = SH + buf * 4096;
    u16* Bd = SH + 12288 + buf * 4096;
    #pragma unroll
    for (int i = 0; i < 2; ++i) {
      const int g = wave * 2 + i;
      __builtin_amdgcn_global_load_lds(
          (const u16*)(Xc + (size_t)(m0 + g * 16 + lrow) * 2048 + kbyte + lchk),
          Ad + g * 512, 16, 0, 0);
      __builtin_amdgcn_global_load_lds(
          (const u16*)(Wc + (size_t)(j0 + g * 16 + lrow) * 2048 + kbyte + lchk),
          Bd + g * 512, 16, 0, 0);
    }
  };

  auto COMPUTE = [&](int cb) {
    const u16* As = SH + cb * 4096;
    const u16* Bs = SH + 12288 + cb * 4096;
    short8 af[4], bf[4];
    #pragma unroll
    for (int mi = 0; mi < 4; ++mi)
      af[mi] = *(const short8*)(&As[(wm * 64 + mi * 16 + r) * 32 + fchk]);
    #pragma unroll
    for (int ji = 0; ji < 4; ++ji)
      bf[ji] = *(const short8*)(&Bs[(wn * 64 + ji * 16 + r) * 32 + fchk]);
    #pragma unroll
    for (int mi = 0; mi < 4; ++mi)
      #pragma unroll
      for (int ji = 0; ji < 4; ++ji)
        acc[mi][ji] = __builtin_amdgcn_mfma_f32_16x16x32_bf16(af[mi], bf[ji], acc[mi][ji], 0, 0, 0);
  };

  STAGE(0, 0);
  STAGE(1, 1);
  int cb = 0;
  for (int kt = 0; kt < 31; ++kt) {
    asm volatile("s_waitcnt vmcnt(4) lgkmcnt(0)\n\ts_barrier" ::: "memory");
    if (kt < 30) {
      int nb = cb + 2; if (nb >= 3) nb -= 3;
      STAGE(nb, kt + 2);
    }
    COMPUTE(cb);
    if (++cb == 3) cb = 0;
  }
  asm volatile("s_waitcnt vmcnt(0) lgkmcnt(0)\n\ts_barrier" ::: "memory");
  COMPUTE(cb);

  __syncthreads();
  const int h0 = (j0 & 1023) >> 6;
  const int t0 = mt * 32;
  if (src < 2) {
    #pragma unroll
    for (int mi = 0; mi < 4; ++mi) {
      const int tt = wm * 16 + mi * 4 + q4;
      #pragma unroll
      for (int ji = 0; ji < 4; ++ji) {
        const int jj = wn * 64 + ji * 16 + r;
        const int dd = jj & 63, hq = jj >> 6;
        const int cs = (((dd >> 3) ^ (tt & 7)) << 3) + (dd & 7);
        #pragma unroll
        for (int rr = 0; rr < 4; ++rr) {
          float v = acc[mi][ji][rr] + bias[j0 + jj];
          SH[((rr * 2 + hq) * 32 + tt) * 64 + cs] =
              (src == 0) ? f2bf(v * 0.125f) : f2bf(v);
        }
      }
    }
    __syncthreads();
    u16* dst = (src == 0) ? qh : kh;
    #pragma unroll
    for (int c = 0; c < 8; ++c) {
      const int cid = c * 256 + tid;
      const int nn = cid >> 9, hq = (cid >> 8) & 1, tt = (cid >> 3) & 31, dc = cid & 7;
      short8 vv = *(const short8*)(SH + ((nn * 2 + hq) * 32 + tt) * 64 +
                                   ((dc ^ (tt & 7)) << 3));
      *(short8*)(dst + (size_t)(nn * 16 + h0 + hq) * 65536 +
                 (size_t)(t0 + tt) * 64 + dc * 8) = vv;
    }
  } else {
    #pragma unroll
    for (int mi = 0; mi < 4; ++mi) {
      const int tt = wm * 16 + mi * 4 + q4;
      const int tc = tt >> 3, toff = tt & 7;
      #pragma unroll
      for (int ji = 0; ji < 4; ++ji) {
        const int jj = wn * 64 + ji * 16 + r;
        const int dd = jj & 63, hq = jj >> 6;
        #pragma unroll
        for (int rr = 0; rr < 4; ++rr) {
          float v = acc[mi][ji][rr] + bias[j0 + jj];
          SH[((rr * 2 + hq) * 64 + dd) * 32 + ((tc ^ (dd & 3)) << 3) + toff] = f2bf(v);
        }
      }
    }
    __syncthreads();
    #pragma unroll
    for (int c = 0; c < 8; ++c) {
      const int cid = c * 256 + tid;
      const int bbv = cid >> 8, dd = (cid >> 2) & 63, tc = cid & 3;
      short8 vv = *(const short8*)(SH + (bbv * 64 + dd) * 32 +
                                   ((tc ^ (dd & 3)) << 3));
      const int bb = (bbv >> 1) * 16 + h0 + (bbv & 1);
      *(short8*)(vt + (size_t)bb * 65536 + (size_t)dd * 1024 + t0 + tc * 8) = vv;
    }
  }
}

// ---------------------------------------------------------------------------
// Kernel 2: attention context. (r17 body) Round-20: XCD co-location remap --
// hw = b*8+lt previously spread one head's 8 blocks over 8 XCDs; now XCD x
// (hw&7) owns b in [8x,8x+8), so each head's K/V is L2-resident on one XCD.
// ---------------------------------------------------------------------------
__global__ __launch_bounds__(512) void attn_ctx_mfma(
    const u16* __restrict__ qh, const u16* __restrict__ kh,
    const u16* __restrict__ vt, u16* __restrict__ ctx,
    float* __restrict__ Zbuf)
{
  __shared__ __align__(16) u16 Ks[2][4096];   // 64 rows x 8 chunks x 8 bf16
  __shared__ __align__(16) u16 Vs[2][4096];
  __shared__ __align__(16) u16 Pl[8][1024];   // per-wave P[16][64], swizzled

  const int tid = threadIdx.x;
  const int wv = tid >> 6, lane = tid & 63, r = lane & 15, q4 = lane >> 4;
  // XCD co-location: hw in [0,512); xcd = hw&7 owns b in [xcd*8, xcd*8+8).
  const int hw  = blockIdx.y * 8 + blockIdx.x;
  const int jj2 = hw >> 3;
  const int b   = (hw & 7) * 8 + (jj2 >> 3);
  const int lw  = (jj2 & 7) * 128 + wv * 16;
  const int n = b >> 4, h = b & 15;

  const u16* qbase = qh + (size_t)b * 65536;
  const char* kc = (const char*)(kh + (size_t)b * 65536);
  const char* vc = (const char*)(vt + (size_t)b * 65536);
  u16* P = Pl[wv];

  const int ls  = lane >> 3;               // row-in-octet 0..7
  const int swzb = ((lane & 7) ^ ls) << 4; // swizzled 16B-chunk byte offset
  const size_t klo = (size_t)wv * 1024  + (size_t)ls * 128  + swzb;  // K row = 128 B
  const size_t vlo = (size_t)wv * 16384 + (size_t)ls * 2048 + swzb;  // V row = 2048 B

  const int rsw = r & 7;
  const int c0 = (q4 ^ rsw) << 3;          // u16 offset of logical chunk q4
  const int c1 = ((q4 ^ rsw) ^ 4) << 3;    // logical chunk q4+4

  short8 aq0 = *(const short8*)(qbase + (size_t)(lw + r) * 64 + q4 * 8);
  short8 aq1 = *(const short8*)(qbase + (size_t)(lw + r) * 64 + 32 + q4 * 8);

  f32x4 oc[4];
  #pragma unroll
  for (int ji = 0; ji < 4; ++ji) oc[ji] = (f32x4){0.f, 0.f, 0.f, 0.f};
  float z[4] = {0.f, 0.f, 0.f, 0.f};

  {
    __builtin_amdgcn_global_load_lds(kc + klo, &Ks[0][wv * 512], 16, 0, 0);
    __builtin_amdgcn_global_load_lds(vc + vlo, &Vs[0][wv * 512], 16, 0, 0);
  }

  for (int it = 0; it < 16; ++it) {
    const int cur = it & 1;
    __syncthreads();   // drains vmcnt -> Ks/Vs[cur] staged; prev-iter reads done
    const u16* Kb = Ks[cur];
    const u16* Vb = Vs[cur];

    f32x4 sc[4];
    #pragma unroll
    for (int ji = 0; ji < 4; ++ji) {
      const int row = (ji * 16 + r) * 64;
      short8 bk0 = *(const short8*)(Kb + row + c0);
      short8 bk1 = *(const short8*)(Kb + row + c1);
      f32x4 t = (f32x4){0.f, 0.f, 0.f, 0.f};
      t = __builtin_amdgcn_mfma_f32_16x16x32_bf16(aq0, bk0, t, 0, 0, 0);
      t = __builtin_amdgcn_mfma_f32_16x16x32_bf16(aq1, bk1, t, 0, 0, 0);
      sc[ji] = t;
    }

    if (it < 15) {
      __builtin_amdgcn_global_load_lds(kc + (size_t)(it + 1) * 8192 + klo,
                                       &Ks[cur ^ 1][wv * 512], 16, 0, 0);
      __builtin_amdgcn_global_load_lds(vc + (size_t)(it + 1) * 128 + vlo,
                                       &Vs[cur ^ 1][wv * 512], 16, 0, 0);
    }

    #pragma unroll
    for (int ji = 0; ji < 4; ++ji) {
      const int cw = ji * 2 + (r >> 3);   // logical 8-elt chunk of col ji*16+r
      #pragma unroll
      for (int rr = 0; rr < 4; ++rr) {
        float e = __expf(sc[ji][rr]);
        z[rr] += e;
        const int row = q4 * 4 + rr;
        P[row * 64 + ((cw ^ (row & 7)) << 3) + (r & 7)] = f2bf(e);
      }
    }
    asm volatile("s_waitcnt lgkmcnt(0)" ::: "memory");
    short8 ap0 = *(const short8*)(P + r * 64 + c0);
    short8 ap1 = *(const short8*)(P + r * 64 + c1);
    #pragma unroll
    for (int ji = 0; ji < 4; ++ji) {
      const int row = (ji * 16 + r) * 64;
      short8 bv0 = *(const short8*)(Vb + row + c0);
      short8 bv1 = *(const short8*)(Vb + row + c1);
      oc[ji] = __builtin_amdgcn_mfma_f32_16x16x32_bf16(ap0, bv0, oc[ji], 0, 0, 0);
      oc[ji] = __builtin_amdgcn_mfma_f32_16x16x32_bf16(ap1, bv1, oc[ji], 0, 0, 0);
    }
  }

  #pragma unroll
  for (int rr = 0; rr < 4; ++rr) {
    float zz = z[rr];
    zz += __shfl_xor(zz, 1);
    zz += __shfl_xor(zz, 2);
    zz += __shfl_xor(zz, 4);
    zz += __shfl_xor(zz, 8);
    z[rr] = zz;
  }

  #pragma unroll
  for (int rr = 0; rr < 4; ++rr) {
    float inv = 1.0f / z[rr];
    int l = lw + q4 * 4 + rr;
    u16* crow = ctx + ((size_t)l * 4 + n) * 1024 + h * 64;
    #pragma unroll
    for (int ji = 0; ji < 4; ++ji)
      crow[ji * 16 + r] = f2bf(oc[ji][rr] * inv);
    if (r == 0) Zbuf[(size_t)b * 1024 + l] = z[rr];
  }
}

// ---------------------------------------------------------------------------
// Kernel 3: fused tail -- out_gemm (blocks 0..511) + attn_w (blocks 512..1535).
// Round-20: attn_w XCD co-location -- XCD x owns (n,st) combos [8x,8x+8),
// lt fastest (16 consecutive blocks share each K-slab; per-XCD working set
// kh-slab 1MB + qh[n] 2MB <= 4MB L2). out_gemm branch unchanged (r13).
// ---------------------------------------------------------------------------
__global__ __launch_bounds__(256) void tail_fused(
    const u16* __restrict__ qh, const u16* __restrict__ kh,
    const float* __restrict__ Zbuf, float* __restrict__ out_w,
    const u16* __restrict__ ctx, const u16* __restrict__ W,
    const float* __restrict__ bias, float* __restrict__ out)
{
  __shared__ __align__(16) u16 SH[18432];   // 36 KB

  const int tid = threadIdx.x;
  const int wv = tid >> 6, lane = tid & 63, r = lane & 15, q4 = lane >> 4;

  if (blockIdx.x < 512) {
    // ---------------- out_gemm body (r13, verified) ----------------
    const int wave = wv;
    const int wm   = wave >> 1;
    const int wn   = wave & 1;
    const int orig = blockIdx.x;
    const int nid  = (orig & 7) * 64 + (orig >> 3);
    const int mt   = nid >> 4;
    const int jt   = nid & 15;
    const int m0 = mt * 128;
    const int j0 = jt * 64;

    const int lrow = lane >> 2;
    const int lchk = ((lane & 3) ^ ((lane >> 3) & 3)) << 4;
    const char* Ac = (const char*)ctx;
    const char* Wc = (const char*)W;
    const int fchk = (q4 ^ ((r >> 1) & 3)) << 3;

    f32x4 acc[4][2];
    #pragma unroll
    for (int a = 0; a < 4; ++a)
      #pragma unroll
      for (int b = 0; b < 2; ++b)
        acc[a][b] = (f32x4){0.f, 0.f, 0.f, 0.f};

    auto STAGE = [&](int buf, int kt) {   // 3 gload_lds per wave
      const int kbyte = kt * 64;
      u16* Ad = SH + buf * 4096;
      u16* Bd = SH + 12288 + buf * 2048;
      #pragma unroll
      for (int i = 0; i < 2; ++i) {
        const int g = wave * 2 + i;
        __builtin_amdgcn_global_load_lds(
            (const u16*)(Ac + (size_t)(m0 + g * 16 + lrow) * 2048 + kbyte + lchk),
            Ad + g * 512, 16, 0, 0);
      }
      __builtin_amdgcn_global_load_lds(
          (const u16*)(Wc + (size_t)(j0 + wave * 16 + lrow) * 2048 + kbyte + lchk),
          Bd + wave * 512, 16, 0, 0);
    };

    auto COMPUTE = [&](int cb) {
      const u16* As = SH + cb * 4096;
      const u16* Bs = SH + 12288 + cb * 2048;
      short8 af[4], bf[2];
      #pragma unroll
      for (int mi = 0; mi < 4; ++mi)
        af[mi] = *(const short8*)(&As[(wm * 64 + mi * 16 + r) * 32 + fchk]);
      #pragma unroll
      for (int ji = 0; ji < 2; ++ji)
        bf[ji] = *(const short8*)(&Bs[(wn * 32 + ji * 16 + r) * 32 + fchk]);
      #pragma unroll
      for (int mi = 0; mi < 4; ++mi)
        #pragma unroll
        for (int ji = 0; ji < 2; ++ji)
          acc[mi][ji] = __builtin_amdgcn_mfma_f32_16x16x32_bf16(af[mi], bf[ji], acc[mi][ji], 0, 0, 0);
    };

    STAGE(0, 0);
    STAGE(1, 1);
    int cb = 0;
    for (int kt = 0; kt < 31; ++kt) {
      asm volatile("s_waitcnt vmcnt(3) lgkmcnt(0)\n\ts_barrier" ::: "memory");
      if (kt < 30) {
        int nb = cb + 2; if (nb >= 3) nb -= 3;
        STAGE(nb, kt + 2);
      }
      COMPUTE(cb);
      if (++cb == 3) cb = 0;
    }
    asm volatile("s_waitcnt vmcnt(0) lgkmcnt(0)\n\ts_barrier" ::: "memory");
    COMPUTE(cb);

    #pragma unroll
    for (int mi = 0; mi < 4; ++mi) {
      #pragma unroll
      for (int ji = 0; ji < 2; ++ji) {
        #pragma unroll
        for (int rr = 0; rr < 4; ++rr) {
          int m = m0 + wm * 64 + mi * 16 + q4 * 4 + rr;
          int j = j0 + wn * 32 + ji * 16 + r;
          out[(size_t)m * 1024 + j] = acc[mi][ji][rr] + bias[j];
        }
      }
    }
  } else {
    // ---------------- attn_w body (r16 sync structure) ----------------
    // XCD co-location: id2 in [0,1024); xcd = id2&7 owns combos
    // [xcd*8, xcd*8+8) where combo = n*16+st; lt fastest.
    const int id2 = blockIdx.x - 512;
    const int jw  = id2 >> 3;
    const int combo = (id2 & 7) * 8 + (jw >> 4);
    const int lt = jw & 15;
    const int st = combo & 15;
    const int n  = combo >> 4;
    const int l0 = lt * 64;
    const int s0 = st * 64;
    const int lw = l0 + wv * 16;

    u16* Kw = SH;                              // 3 x 4096 u16 = 24 KB
    float* invZ = (float*)(SH + 12288);        // 16*64 floats = 4 KB

    const char* khc = (const char*)kh + (size_t)n * 2097152;

    const int ls  = lane >> 3;
    const int swzb = ((lane & 7) ^ ls) << 4;
    const int iw  = wv * 2;
    const size_t klo = (size_t)s0 * 128 + (size_t)iw * 1024 + (size_t)ls * 128 + swzb;

    const int rsw = r & 7;
    const int c0 = (q4 ^ rsw) << 3;
    const int c1 = ((q4 ^ rsw) ^ 4) << 3;

    for (int i = tid; i < 1024; i += 256) {
      int hh = i >> 6, row = i & 63;
      invZ[hh * 64 + row] = 1.0f / (Zbuf[(size_t)(n * 16 + hh) * 1024 + l0 + row] * 16.0f);
    }

    auto STAGEK = [&](int buf, int hh) {   // 2 gload_lds per wave
      const char* kp = khc + (size_t)hh * 131072 + klo;
      u16* kd = &Kw[buf * 4096 + iw * 512];
      __builtin_amdgcn_global_load_lds(kp,        kd,       16, 0, 0);
      __builtin_amdgcn_global_load_lds(kp + 1024, kd + 512, 16, 0, 0);
    };

    STAGEK(0, 0);
    STAGEK(1, 1);
    const u16* q0 = qh + (size_t)(n * 16) * 65536;
    short8 aqc0 = *(const short8*)(q0 + (size_t)(lw + r) * 64 + q4 * 8);
    short8 aqc1 = *(const short8*)(q0 + (size_t)(lw + r) * 64 + 32 + q4 * 8);

    f32x4 wacc[4];
    #pragma unroll
    for (int ji = 0; ji < 4; ++ji) wacc[ji] = (f32x4){0.f, 0.f, 0.f, 0.f};

    auto HEAD = [&](int hh, int cbw, short8& an0, short8& an1) {
      const int hn = (hh < 15) ? hh + 1 : hh;
      const u16* qn = qh + (size_t)(n * 16 + hn) * 65536;
      an0 = *(const short8*)(qn + (size_t)(lw + r) * 64 + q4 * 8);
      an1 = *(const short8*)(qn + (size_t)(lw + r) * 64 + 32 + q4 * 8);
      if (hh < 14) {
        int nb = cbw + 2; if (nb >= 3) nb -= 3;
        STAGEK(nb, hh + 2);
      }
      const u16* Kb = Kw + cbw * 4096;
      f32x4 sc[4];
      #pragma unroll
      for (int ji = 0; ji < 4; ++ji) {
        const int row = (ji * 16 + r) * 64;
        short8 bk0 = *(const short8*)(Kb + row + c0);
        short8 bk1 = *(const short8*)(Kb + row + c1);
        f32x4 t = (f32x4){0.f, 0.f, 0.f, 0.f};
        t = __builtin_amdgcn_mfma_f32_16x16x32_bf16(aqc0, bk0, t, 0, 0, 0);
        t = __builtin_amdgcn_mfma_f32_16x16x32_bf16(aqc1, bk1, t, 0, 0, 0);
        sc[ji] = t;
      }
      #pragma unroll
      for (int rr = 0; rr < 4; ++rr) {
        float iv = invZ[hh * 64 + wv * 16 + q4 * 4 + rr];
        #pragma unroll
        for (int ji = 0; ji < 4; ++ji)
          wacc[ji][rr] += __expf(sc[ji][rr]) * iv;
      }
      aqc0 = an0; aqc1 = an1;
    };

    int cbw = 0;
    short8 an0, an1;
    for (int hh = 0; hh < 15; ++hh) {
      asm volatile("s_waitcnt vmcnt(4) lgkmcnt(0)\n\ts_barrier" ::: "memory");
      HEAD(hh, cbw, an0, an1);
      if (++cbw == 3) cbw = 0;
    }
    asm volatile("s_waitcnt vmcnt(0) lgkmcnt(0)\n\ts_barrier" ::: "memory");
    HEAD(15, cbw, an0, an1);

    #pragma unroll
    for (int ji = 0; ji < 4; ++ji)
      #pragma unroll
      for (int rr = 0; rr < 4; ++rr) {
        int row = lw + q4 * 4 + rr;
        int col = s0 + ji * 16 + r;
        out_w[(size_t)n * 1048576 + (size_t)row * 1024 + col] = wacc[ji][rr];
      }
  }
}

// ---------------------------------------------------------------------------
extern "C" void kernel_launch(void* const* d_in, const int* in_sizes, int n_in,
                              void* d_out, int out_size, void* d_ws, size_t ws_size,
                              hipStream_t stream) {
  const float* query = (const float*)d_in[0];
  const float* key   = (const float*)d_in[1];
  const float* value = (const float*)d_in[2];
  const float* W_in  = (const float*)d_in[3];
  const float* b_in  = (const float*)d_in[4];
  const float* W_out = (const float*)d_in[5];
  const float* b_out = (const float*)d_in[6];
  float* out = (float*)d_out;

  // ws (~64.3 MB): qb 8 | kb 8 | vb 8 | Wib 6 | Wob 2 | qh 8 | kh 8 | vt 8 | ctx 8 | Z .25
  u16* qb  = (u16*)d_ws;
  u16* kb  = qb  + (size_t)4194304;
  u16* vb  = kb  + (size_t)4194304;
  u16* Wib = vb  + (size_t)4194304;
  u16* Wob = Wib + (size_t)3145728;
  u16* qh  = Wob + (size_t)1048576;
  u16* kh  = qh  + (size_t)4194304;
  u16* vt  = kh  + (size_t)4194304;
  u16* ctx = vt  + (size_t)4194304;
  float* Zbuf = (float*)(ctx + (size_t)4194304);

  convert_bf16<<<dim3(512, 5), 256, 0, stream>>>(query, key, value, W_in, W_out,
                                                 qb, kb, vb, Wib, Wob);
  qkv_gemm<<<dim3(24, 32), 256, 0, stream>>>(qb, kb, vb, Wib, b_in, qh, kh, vt);
  attn_ctx_mfma<<<dim3(8, 64), 512, 0, stream>>>(qh, kh, vt, ctx, Zbuf);
  tail_fused<<<dim3(1536), 256, 0, stream>>>(qh, kh, Zbuf, out + (size_t)4194304,
                                             ctx, Wob, b_out, out);
}

// Round 15
// 215.121 us; speedup vs baseline: 1.0204x; 1.0204x over previous
//
#include <hip/hip_runtime.h>

// MHA forward. L=S=1024, N=4, E=1024, H=16, hd=64, B=N*H=64, M=L*N=4096
// Inputs fp32, outputs fp32 (out0=attn_output 4.19M, out1=attn_weights 4.19M @+4194304).
// Round 21: FINAL -- restore best-measured config (r17/r19: 213.9/216.2us).
// r20's XCD remap halved attention FETCH (49->26MB) but time was null-to-
// slightly-negative -> attention kernels are latency-bound, not L2-BW-bound
// (T1's null regime). Ledger: qkv counted-vmcnt +18% (r13; 8-phase/256^2
// structurally inapplicable -- 192 tiles < 256 CUs); attn_w schedule null
// (r16); attn_ctx widening +10us (r17); tail fusion +8us (r15); epilogue
// coalescing +10us (r10); convert fusion refuted (r18); XCD remap time-null
// (r20). Remaining: 41.5us harness ws-fill + BW-bound convert + three
// kernels with all schedule levers measured-null.
typedef unsigned short u16;
typedef __attribute__((ext_vector_type(8))) short short8;   // 8 bf16 (4 VGPRs)
typedef __attribute__((ext_vector_type(4))) float f32x4;    // MFMA accumulator

__device__ __forceinline__ u16 f2bf(float f) {  // RNE
  unsigned int i = __float_as_uint(f);
  i += 0x7fffu + ((i >> 16) & 1u);
  return (u16)(i >> 16);
}

__device__ __forceinline__ short8 cvt8(const float* p) {
  float4 a = ((const float4*)p)[0];
  float4 b = ((const float4*)p)[1];
  short8 r;
  r[0] = (short)f2bf(a.x); r[1] = (short)f2bf(a.y);
  r[2] = (short)f2bf(a.z); r[3] = (short)f2bf(a.w);
  r[4] = (short)f2bf(b.x); r[5] = (short)f2bf(b.y);
  r[6] = (short)f2bf(b.z); r[7] = (short)f2bf(b.w);
  return r;
}

// ---------------------------------------------------------------------------
// Kernel 0: one-shot fp32 -> bf16 conversion of q/k/v/W_in/W_out.
// ---------------------------------------------------------------------------
__global__ __launch_bounds__(256) void convert_bf16(
    const float* __restrict__ q, const float* __restrict__ k,
    const float* __restrict__ v, const float* __restrict__ Wi,
    const float* __restrict__ Wo,
    u16* __restrict__ qb, u16* __restrict__ kb, u16* __restrict__ vb,
    u16* __restrict__ Wib, u16* __restrict__ Wob)
{
  const float* src; u16* dst; int len8;
  switch (blockIdx.y) {
    case 0:  src = q;  dst = qb;  len8 = 524288; break;  // 4M elts
    case 1:  src = k;  dst = kb;  len8 = 524288; break;
    case 2:  src = v;  dst = vb;  len8 = 524288; break;
    case 3:  src = Wi; dst = Wib; len8 = 393216; break;  // 3M elts
    default: src = Wo; dst = Wob; len8 = 131072; break;  // 1M elts
  }
  int stride = gridDim.x * 256;
  for (int i = blockIdx.x * 256 + threadIdx.x; i < len8; i += stride)
    *(short8*)(dst + (size_t)i * 8) = cvt8(src + (size_t)i * 8);
}

// ---------------------------------------------------------------------------
// Kernel 1: packed QKV projection. (r13, verified)
// 128x128 tile, BK=32, 3-buffer counted-vmcnt pipeline, coalesced epilogue.
// ---------------------------------------------------------------------------
__global__ __launch_bounds__(256) void qkv_gemm(
    const u16* __restrict__ qb, const u16* __restrict__ kb,
    const u16* __restrict__ vb, const u16* __restrict__ W,
    const float* __restrict__ bias,
    u16* __restrict__ qh, u16* __restrict__ kh, u16* __restrict__ vt)
{
  __shared__ __align__(16) u16 SH[24576];

  const int tid  = threadIdx.x;
  const int wave = tid >> 6;
  const int lane = tid & 63;
  const int r    = lane & 15;
  const int q4   = lane >> 4;
  const int wm   = wave >> 1;
  const int wn   = wave & 1;

  const int orig = blockIdx.y * 24 + blockIdx.x;
  const int nid  = (orig & 7) * 96 + (orig >> 3);
  const int mt   = nid / 24;
  const int jt   = nid - mt * 24;
  const int src  = jt >> 3;
  const u16* X = (src == 0) ? qb : (src == 1) ? kb : vb;
  const int m0 = mt * 128;
  const int j0 = jt * 128;

  const int lrow = lane >> 2;
  const int lchk = ((lane & 3) ^ ((lane >> 3) & 3)) << 4;
  const char* Xc = (const char*)X;
  const char* Wc = (const char*)W;
  const int fchk = (q4 ^ ((r >> 1) & 3)) << 3;

  f32x4 acc[4][4];
  #pragma unroll
  for (int a = 0; a < 4; ++a)
    #pragma unroll
    for (int b = 0; b < 4; ++b)
      acc[a][b] = (f32x4){0.f, 0.f, 0.f, 0.f};

  auto STAGE = [&](int buf, int kt) {   // 4 gload_lds per wave
    const int kbyte = kt * 64;
    u16* Ad = SH + buf * 4096;
    u16* Bd = SH + 12288 + buf * 4096;
    #pragma unroll
    for (int i = 0; i < 2; ++i) {
      const int g = wave * 2 + i;
      __builtin_amdgcn_global_load_lds(
          (const u16*)(Xc + (size_t)(m0 + g * 16 + lrow) * 2048 + kbyte + lchk),
          Ad + g * 512, 16, 0, 0);
      __builtin_amdgcn_global_load_lds(
          (const u16*)(Wc + (size_t)(j0 + g * 16 + lrow) * 2048 + kbyte + lchk),
          Bd + g * 512, 16, 0, 0);
    }
  };

  auto COMPUTE = [&](int cb) {
    const u16* As = SH + cb * 4096;
    const u16* Bs = SH + 12288 + cb * 4096;
    short8 af[4], bf[4];
    #pragma unroll
    for (int mi = 0; mi < 4; ++mi)
      af[mi] = *(const short8*)(&As[(wm * 64 + mi * 16 + r) * 32 + fchk]);
    #pragma unroll
    for (int ji = 0; ji < 4; ++ji)
      bf[ji] = *(const short8*)(&Bs[(wn * 64 + ji * 16 + r) * 32 + fchk]);
    #pragma unroll
    for (int mi = 0; mi < 4; ++mi)
      #pragma unroll
      for (int ji = 0; ji < 4; ++ji)
        acc[mi][ji] = __builtin_amdgcn_mfma_f32_16x16x32_bf16(af[mi], bf[ji], acc[mi][ji], 0, 0, 0);
  };

  STAGE(0, 0);
  STAGE(1, 1);
  int cb = 0;
  for (int kt = 0; kt < 31; ++kt) {
    asm volatile("s_waitcnt vmcnt(4) lgkmcnt(0)\n\ts_barrier" ::: "memory");
    if (kt < 30) {
      int nb = cb + 2; if (nb >= 3) nb -= 3;
      STAGE(nb, kt + 2);
    }
    COMPUTE(cb);
    if (++cb == 3) cb = 0;
  }
  asm volatile("s_waitcnt vmcnt(0) lgkmcnt(0)\n\ts_barrier" ::: "memory");
  COMPUTE(cb);

  __syncthreads();
  const int h0 = (j0 & 1023) >> 6;
  const int t0 = mt * 32;
  if (src < 2) {
    #pragma unroll
    for (int mi = 0; mi < 4; ++mi) {
      const int tt = wm * 16 + mi * 4 + q4;
      #pragma unroll
      for (int ji = 0; ji < 4; ++ji) {
        const int jj = wn * 64 + ji * 16 + r;
        const int dd = jj & 63, hq = jj >> 6;
        const int cs = (((dd >> 3) ^ (tt & 7)) << 3) + (dd & 7);
        #pragma unroll
        for (int rr = 0; rr < 4; ++rr) {
          float v = acc[mi][ji][rr] + bias[j0 + jj];
          SH[((rr * 2 + hq) * 32 + tt) * 64 + cs] =
              (src == 0) ? f2bf(v * 0.125f) : f2bf(v);
        }
      }
    }
    __syncthreads();
    u16* dst = (src == 0) ? qh : kh;
    #pragma unroll
    for (int c = 0; c < 8; ++c) {
      const int cid = c * 256 + tid;
      const int nn = cid >> 9, hq = (cid >> 8) & 1, tt = (cid >> 3) & 31, dc = cid & 7;
      short8 vv = *(const short8*)(SH + ((nn * 2 + hq) * 32 + tt) * 64 +
                                   ((dc ^ (tt & 7)) << 3));
      *(short8*)(dst + (size_t)(nn * 16 + h0 + hq) * 65536 +
                 (size_t)(t0 + tt) * 64 + dc * 8) = vv;
    }
  } else {
    #pragma unroll
    for (int mi = 0; mi < 4; ++mi) {
      const int tt = wm * 16 + mi * 4 + q4;
      const int tc = tt >> 3, toff = tt & 7;
      #pragma unroll
      for (int ji = 0; ji < 4; ++ji) {
        const int jj = wn * 64 + ji * 16 + r;
        const int dd = jj & 63, hq = jj >> 6;
        #pragma unroll
        for (int rr = 0; rr < 4; ++rr) {
          float v = acc[mi][ji][rr] + bias[j0 + jj];
          SH[((rr * 2 + hq) * 64 + dd) * 32 + ((tc ^ (dd & 3)) << 3) + toff] = f2bf(v);
        }
      }
    }
    __syncthreads();
    #pragma unroll
    for (int c = 0; c < 8; ++c) {
      const int cid = c * 256 + tid;
      const int bbv = cid >> 8, dd = (cid >> 2) & 63, tc = cid & 3;
      short8 vv = *(const short8*)(SH + (bbv * 64 + dd) * 32 +
                                   ((tc ^ (dd & 3)) << 3));
      const int bb = (bbv >> 1) * 16 + h0 + (bbv & 1);
      *(short8*)(vt + (size_t)bb * 65536 + (size_t)dd * 1024 + t0 + tc * 8) = vv;
    }
  }
}

// ---------------------------------------------------------------------------
// Kernel 2: attention context. (r17, verified) 512 threads / 128 Q-rows per
// block (grid 8 x 64); 8 waves share each staged K/V tile. LDS 48 KB.
// ---------------------------------------------------------------------------
__global__ __launch_bounds__(512) void attn_ctx_mfma(
    const u16* __restrict__ qh, const u16* __restrict__ kh,
    const u16* __restrict__ vt, u16* __restrict__ ctx,
    float* __restrict__ Zbuf)
{
  __shared__ __align__(16) u16 Ks[2][4096];   // 64 rows x 8 chunks x 8 bf16
  __shared__ __align__(16) u16 Vs[2][4096];
  __shared__ __align__(16) u16 Pl[8][1024];   // per-wave P[16][64], swizzled

  const int tid = threadIdx.x;
  const int wv = tid >> 6, lane = tid & 63, r = lane & 15, q4 = lane >> 4;
  const int b  = blockIdx.y;
  const int lw = blockIdx.x * 128 + wv * 16;
  const int n = b >> 4, h = b & 15;

  const u16* qbase = qh + (size_t)b * 65536;
  const char* kc = (const char*)(kh + (size_t)b * 65536);
  const char* vc = (const char*)(vt + (size_t)b * 65536);
  u16* P = Pl[wv];

  const int ls  = lane >> 3;               // row-in-octet 0..7
  const int swzb = ((lane & 7) ^ ls) << 4; // swizzled 16B-chunk byte offset
  const size_t klo = (size_t)wv * 1024  + (size_t)ls * 128  + swzb;  // K row = 128 B
  const size_t vlo = (size_t)wv * 16384 + (size_t)ls * 2048 + swzb;  // V row = 2048 B

  const int rsw = r & 7;
  const int c0 = (q4 ^ rsw) << 3;          // u16 offset of logical chunk q4
  const int c1 = ((q4 ^ rsw) ^ 4) << 3;    // logical chunk q4+4

  short8 aq0 = *(const short8*)(qbase + (size_t)(lw + r) * 64 + q4 * 8);
  short8 aq1 = *(const short8*)(qbase + (size_t)(lw + r) * 64 + 32 + q4 * 8);

  f32x4 oc[4];
  #pragma unroll
  for (int ji = 0; ji < 4; ++ji) oc[ji] = (f32x4){0.f, 0.f, 0.f, 0.f};
  float z[4] = {0.f, 0.f, 0.f, 0.f};

  {
    __builtin_amdgcn_global_load_lds(kc + klo, &Ks[0][wv * 512], 16, 0, 0);
    __builtin_amdgcn_global_load_lds(vc + vlo, &Vs[0][wv * 512], 16, 0, 0);
  }

  for (int it = 0; it < 16; ++it) {
    const int cur = it & 1;
    __syncthreads();   // drains vmcnt -> Ks/Vs[cur] staged; prev-iter reads done
    const u16* Kb = Ks[cur];
    const u16* Vb = Vs[cur];

    f32x4 sc[4];
    #pragma unroll
    for (int ji = 0; ji < 4; ++ji) {
      const int row = (ji * 16 + r) * 64;
      short8 bk0 = *(const short8*)(Kb + row + c0);
      short8 bk1 = *(const short8*)(Kb + row + c1);
      f32x4 t = (f32x4){0.f, 0.f, 0.f, 0.f};
      t = __builtin_amdgcn_mfma_f32_16x16x32_bf16(aq0, bk0, t, 0, 0, 0);
      t = __builtin_amdgcn_mfma_f32_16x16x32_bf16(aq1, bk1, t, 0, 0, 0);
      sc[ji] = t;
    }

    if (it < 15) {
      __builtin_amdgcn_global_load_lds(kc + (size_t)(it + 1) * 8192 + klo,
                                       &Ks[cur ^ 1][wv * 512], 16, 0, 0);
      __builtin_amdgcn_global_load_lds(vc + (size_t)(it + 1) * 128 + vlo,
                                       &Vs[cur ^ 1][wv * 512], 16, 0, 0);
    }

    #pragma unroll
    for (int ji = 0; ji < 4; ++ji) {
      const int cw = ji * 2 + (r >> 3);   // logical 8-elt chunk of col ji*16+r
      #pragma unroll
      for (int rr = 0; rr < 4; ++rr) {
        float e = __expf(sc[ji][rr]);
        z[rr] += e;
        const int row = q4 * 4 + rr;
        P[row * 64 + ((cw ^ (row & 7)) << 3) + (r & 7)] = f2bf(e);
      }
    }
    asm volatile("s_waitcnt lgkmcnt(0)" ::: "memory");
    short8 ap0 = *(const short8*)(P + r * 64 + c0);
    short8 ap1 = *(const short8*)(P + r * 64 + c1);
    #pragma unroll
    for (int ji = 0; ji < 4; ++ji) {
      const int row = (ji * 16 + r) * 64;
      short8 bv0 = *(const short8*)(Vb + row + c0);
      short8 bv1 = *(const short8*)(Vb + row + c1);
      oc[ji] = __builtin_amdgcn_mfma_f32_16x16x32_bf16(ap0, bv0, oc[ji], 0, 0, 0);
      oc[ji] = __builtin_amdgcn_mfma_f32_16x16x32_bf16(ap1, bv1, oc[ji], 0, 0, 0);
    }
  }

  #pragma unroll
  for (int rr = 0; rr < 4; ++rr) {
    float zz = z[rr];
    zz += __shfl_xor(zz, 1);
    zz += __shfl_xor(zz, 2);
    zz += __shfl_xor(zz, 4);
    zz += __shfl_xor(zz, 8);
    z[rr] = zz;
  }

  #pragma unroll
  for (int rr = 0; rr < 4; ++rr) {
    float inv = 1.0f / z[rr];
    int l = lw + q4 * 4 + rr;
    u16* crow = ctx + ((size_t)l * 4 + n) * 1024 + h * 64;
    #pragma unroll
    for (int ji = 0; ji < 4; ++ji)
      crow[ji * 16 + r] = f2bf(oc[ji][rr] * inv);
    if (r == 0) Zbuf[(size_t)b * 1024 + l] = z[rr];
  }
}

// ---------------------------------------------------------------------------
// Kernel 3: fused tail -- out_gemm (blocks 0..511) + attn_w (blocks 512..1535).
// (r16, verified)
// ---------------------------------------------------------------------------
__global__ __launch_bounds__(256) void tail_fused(
    const u16* __restrict__ qh, const u16* __restrict__ kh,
    const float* __restrict__ Zbuf, float* __restrict__ out_w,
    const u16* __restrict__ ctx, const u16* __restrict__ W,
    const float* __restrict__ bias, float* __restrict__ out)
{
  __shared__ __align__(16) u16 SH[18432];   // 36 KB

  const int tid = threadIdx.x;
  const int wv = tid >> 6, lane = tid & 63, r = lane & 15, q4 = lane >> 4;

  if (blockIdx.x < 512) {
    // ---------------- out_gemm body (r13, verified) ----------------
    const int wave = wv;
    const int wm   = wave >> 1;
    const int wn   = wave & 1;
    const int orig = blockIdx.x;
    const int nid  = (orig & 7) * 64 + (orig >> 3);
    const int mt   = nid >> 4;
    const int jt   = nid & 15;
    const int m0 = mt * 128;
    const int j0 = jt * 64;

    const int lrow = lane >> 2;
    const int lchk = ((lane & 3) ^ ((lane >> 3) & 3)) << 4;
    const char* Ac = (const char*)ctx;
    const char* Wc = (const char*)W;
    const int fchk = (q4 ^ ((r >> 1) & 3)) << 3;

    f32x4 acc[4][2];
    #pragma unroll
    for (int a = 0; a < 4; ++a)
      #pragma unroll
      for (int b = 0; b < 2; ++b)
        acc[a][b] = (f32x4){0.f, 0.f, 0.f, 0.f};

    auto STAGE = [&](int buf, int kt) {   // 3 gload_lds per wave
      const int kbyte = kt * 64;
      u16* Ad = SH + buf * 4096;
      u16* Bd = SH + 12288 + buf * 2048;
      #pragma unroll
      for (int i = 0; i < 2; ++i) {
        const int g = wave * 2 + i;
        __builtin_amdgcn_global_load_lds(
            (const u16*)(Ac + (size_t)(m0 + g * 16 + lrow) * 2048 + kbyte + lchk),
            Ad + g * 512, 16, 0, 0);
      }
      __builtin_amdgcn_global_load_lds(
          (const u16*)(Wc + (size_t)(j0 + wave * 16 + lrow) * 2048 + kbyte + lchk),
          Bd + wave * 512, 16, 0, 0);
    };

    auto COMPUTE = [&](int cb) {
      const u16* As = SH + cb * 4096;
      const u16* Bs = SH + 12288 + cb * 2048;
      short8 af[4], bf[2];
      #pragma unroll
      for (int mi = 0; mi < 4; ++mi)
        af[mi] = *(const short8*)(&As[(wm * 64 + mi * 16 + r) * 32 + fchk]);
      #pragma unroll
      for (int ji = 0; ji < 2; ++ji)
        bf[ji] = *(const short8*)(&Bs[(wn * 32 + ji * 16 + r) * 32 + fchk]);
      #pragma unroll
      for (int mi = 0; mi < 4; ++mi)
        #pragma unroll
        for (int ji = 0; ji < 2; ++ji)
          acc[mi][ji] = __builtin_amdgcn_mfma_f32_16x16x32_bf16(af[mi], bf[ji], acc[mi][ji], 0, 0, 0);
    };

    STAGE(0, 0);
    STAGE(1, 1);
    int cb = 0;
    for (int kt = 0; kt < 31; ++kt) {
      asm volatile("s_waitcnt vmcnt(3) lgkmcnt(0)\n\ts_barrier" ::: "memory");
      if (kt < 30) {
        int nb = cb + 2; if (nb >= 3) nb -= 3;
        STAGE(nb, kt + 2);
      }
      COMPUTE(cb);
      if (++cb == 3) cb = 0;
    }
    asm volatile("s_waitcnt vmcnt(0) lgkmcnt(0)\n\ts_barrier" ::: "memory");
    COMPUTE(cb);

    #pragma unroll
    for (int mi = 0; mi < 4; ++mi) {
      #pragma unroll
      for (int ji = 0; ji < 2; ++ji) {
        #pragma unroll
        for (int rr = 0; rr < 4; ++rr) {
          int m = m0 + wm * 64 + mi * 16 + q4 * 4 + rr;
          int j = j0 + wn * 32 + ji * 16 + r;
          out[(size_t)m * 1024 + j] = acc[mi][ji][rr] + bias[j];
        }
      }
    }
  } else {
    // ---------------- attn_w body: 3-buffer counted-vmcnt head loop --------
    const int id2 = blockIdx.x - 512;
    const int lt = id2 & 15;
    const int st = (id2 >> 4) & 15;
    const int n  = id2 >> 8;
    const int l0 = lt * 64;
    const int s0 = st * 64;
    const int lw = l0 + wv * 16;

    u16* Kw = SH;                              // 3 x 4096 u16 = 24 KB
    float* invZ = (float*)(SH + 12288);        // 16*64 floats = 4 KB

    const char* khc = (const char*)kh + (size_t)n * 2097152;

    const int ls  = lane >> 3;
    const int swzb = ((lane & 7) ^ ls) << 4;
    const int iw  = wv * 2;
    const size_t klo = (size_t)s0 * 128 + (size_t)iw * 1024 + (size_t)ls * 128 + swzb;

    const int rsw = r & 7;
    const int c0 = (q4 ^ rsw) << 3;
    const int c1 = ((q4 ^ rsw) ^ 4) << 3;

    for (int i = tid; i < 1024; i += 256) {
      int hh = i >> 6, row = i & 63;
      invZ[hh * 64 + row] = 1.0f / (Zbuf[(size_t)(n * 16 + hh) * 1024 + l0 + row] * 16.0f);
    }

    auto STAGEK = [&](int buf, int hh) {   // 2 gload_lds per wave
      const char* kp = khc + (size_t)hh * 131072 + klo;
      u16* kd = &Kw[buf * 4096 + iw * 512];
      __builtin_amdgcn_global_load_lds(kp,        kd,       16, 0, 0);
      __builtin_amdgcn_global_load_lds(kp + 1024, kd + 512, 16, 0, 0);
    };

    STAGEK(0, 0);
    STAGEK(1, 1);
    const u16* q0 = qh + (size_t)(n * 16) * 65536;
    short8 aqc0 = *(const short8*)(q0 + (size_t)(lw + r) * 64 + q4 * 8);
    short8 aqc1 = *(const short8*)(q0 + (size_t)(lw + r) * 64 + 32 + q4 * 8);

    f32x4 wacc[4];
    #pragma unroll
    for (int ji = 0; ji < 4; ++ji) wacc[ji] = (f32x4){0.f, 0.f, 0.f, 0.f};

    auto HEAD = [&](int hh, int cbw, short8& an0, short8& an1) {
      const int hn = (hh < 15) ? hh + 1 : hh;
      const u16* qn = qh + (size_t)(n * 16 + hn) * 65536;
      an0 = *(const short8*)(qn + (size_t)(lw + r) * 64 + q4 * 8);
      an1 = *(const short8*)(qn + (size_t)(lw + r) * 64 + 32 + q4 * 8);
      if (hh < 14) {
        int nb = cbw + 2; if (nb >= 3) nb -= 3;
        STAGEK(nb, hh + 2);
      }
      const u16* Kb = Kw + cbw * 4096;
      f32x4 sc[4];
      #pragma unroll
      for (int ji = 0; ji < 4; ++ji) {
        const int row = (ji * 16 + r) * 64;
        short8 bk0 = *(const short8*)(Kb + row + c0);
        short8 bk1 = *(const short8*)(Kb + row + c1);
        f32x4 t = (f32x4){0.f, 0.f, 0.f, 0.f};
        t = __builtin_amdgcn_mfma_f32_16x16x32_bf16(aqc0, bk0, t, 0, 0, 0);
        t = __builtin_amdgcn_mfma_f32_16x16x32_bf16(aqc1, bk1, t, 0, 0, 0);
        sc[ji] = t;
      }
      #pragma unroll
      for (int rr = 0; rr < 4; ++rr) {
        float iv = invZ[hh * 64 + wv * 16 + q4 * 4 + rr];
        #pragma unroll
        for (int ji = 0; ji < 4; ++ji)
          wacc[ji][rr] += __expf(sc[ji][rr]) * iv;
      }
      aqc0 = an0; aqc1 = an1;
    };

    int cbw = 0;
    short8 an0, an1;
    for (int hh = 0; hh < 15; ++hh) {
      asm volatile("s_waitcnt vmcnt(4) lgkmcnt(0)\n\ts_barrier" ::: "memory");
      HEAD(hh, cbw, an0, an1);
      if (++cbw == 3) cbw = 0;
    }
    asm volatile("s_waitcnt vmcnt(0) lgkmcnt(0)\n\ts_barrier" ::: "memory");
    HEAD(15, cbw, an0, an1);

    #pragma unroll
    for (int ji = 0; ji < 4; ++ji)
      #pragma unroll
      for (int rr = 0; rr < 4; ++rr) {
        int row = lw + q4 * 4 + rr;
        int col = s0 + ji * 16 + r;
        out_w[(size_t)n * 1048576 + (size_t)row * 1024 + col] = wacc[ji][rr];
      }
  }
}

// ---------------------------------------------------------------------------
extern "C" void kernel_launch(void* const* d_in, const int* in_sizes, int n_in,
                              void* d_out, int out_size, void* d_ws, size_t ws_size,
                              hipStream_t stream) {
  const float* query = (const float*)d_in[0];
  const float* key   = (const float*)d_in[1];
  const float* value = (const float*)d_in[2];
  const float* W_in  = (const float*)d_in[3];
  const float* b_in  = (const float*)d_in[4];
  const float* W_out = (const float*)d_in[5];
  const float* b_out = (const float*)d_in[6];
  float* out = (float*)d_out;

  // ws (~64.3 MB): qb 8 | kb 8 | vb 8 | Wib 6 | Wob 2 | qh 8 | kh 8 | vt 8 | ctx 8 | Z .25
  u16* qb  = (u16*)d_ws;
  u16* kb  = qb  + (size_t)4194304;
  u16* vb  = kb  + (size_t)4194304;
  u16* Wib = vb  + (size_t)4194304;
  u16* Wob = Wib + (size_t)3145728;
  u16* qh  = Wob + (size_t)1048576;
  u16* kh  = qh  + (size_t)4194304;
  u16* vt  = kh  + (size_t)4194304;
  u16* ctx = vt  + (size_t)4194304;
  float* Zbuf = (float*)(ctx + (size_t)4194304);

  convert_bf16<<<dim3(512, 5), 256, 0, stream>>>(query, key, value, W_in, W_out,
                                                 qb, kb, vb, Wib, Wob);
  qkv_gemm<<<dim3(24, 32), 256, 0, stream>>>(qb, kb, vb, Wib, b_in, qh, kh, vt);
  attn_ctx_mfma<<<dim3(8, 64), 512, 0, stream>>>(qh, kh, vt, ctx, Zbuf);
  tail_fused<<<dim3(1536), 256, 0, stream>>>(qh, kh, Zbuf, out + (size_t)4194304,
                                             ctx, Wob, b_out, out);
}